// Round 4
// baseline (1292.071 us; speedup 1.0000x reference)
//
#include <hip/hip_runtime.h>
#include <math.h>

#define H 4096
#define E 64
#define TOPK 8
#define EPS 2e-4f
#define R 16          // rows per block
#define KC 1024       // k-extent per wave (4 waves cover K=4096)
#define BT 32         // k-tile
#define NT (KC / BT)  // 32 tiles per wave

__global__ void init_cnt_kernel(unsigned int* cnt) {
    if (threadIdx.x == 0) cnt[0] = 0u;
}

// lane = expert. Wave w of 4 handles rows [row0,row0+16) over k in [w*1024,(w+1)*1024).
// W fragment: LDS (wave-private, xor-swizzled) -> 32 VGPRs per tile, reused over 16 rows.
// A chunk: wave-uniform scalar loads (no threadIdx in address) -> SGPRs, depth-2 prefetch.
// No __syncthreads in the main loop. Cross-wave k-reduce in LDS at the end.
__global__ __launch_bounds__(256) void router_gemm_kernel(
    const float* __restrict__ A, const float* __restrict__ Wm,
    const float* __restrict__ bias, float* __restrict__ weights,
    float* __restrict__ indices, float* __restrict__ probs,
    unsigned int* __restrict__ cnt, unsigned int* __restrict__ list, int T)
{
    __shared__ float lds[4 * E * BT];   // 32 KB: per-wave W tiles; reused as Lred[4][16][64]

    const int tid  = threadIdx.x;
    const int lane = tid & 63;
    const int wid  = __builtin_amdgcn_readfirstlane(tid >> 6);
    const long row0 = (long)blockIdx.x * R;
    const int  k0   = wid * KC;

    float* Wt = lds + wid * (E * BT);   // wave-private [64 e][32 k], xor-swizzled 16B chunks

    const int we   = lane >> 3;   // staging expert base (e = we + 8p)
    const int wseg = lane & 7;    // staging 16B chunk

    float acc[R];
#pragma unroll
    for (int r = 0; r < R; ++r) acc[r] = 0.0f;

    // prefetch W tile 0
    float4 wpre[8];
#pragma unroll
    for (int p = 0; p < 8; ++p)
        wpre[p] = *(const float4*)(Wm + (long)(we + 8 * p) * H + k0 + wseg * 4);

#pragma unroll 1
    for (int t = 0; t < NT; ++t) {
        // staged W tile -> LDS (xor swizzle on 16B chunk index)
#pragma unroll
        for (int p = 0; p < 8; ++p) {
            const int e = we + 8 * p;
            *(float4*)&Wt[e * BT + ((wseg ^ (e & 7)) * 4)] = wpre[p];
        }
        // W fragment for my expert (lane) -> 32 VGPRs
        float4 wf[8];
#pragma unroll
        for (int g = 0; g < 8; ++g)
            wf[g] = *(const float4*)&Wt[lane * BT + ((g ^ (lane & 7)) * 4)];
        // prefetch next W tile (in flight across the FMA block)
        if (t + 1 < NT) {
#pragma unroll
            for (int p = 0; p < 8; ++p)
                wpre[p] = *(const float4*)(Wm + (long)(we + 8 * p) * H + k0 + (t + 1) * BT + wseg * 4);
        }

        const float* Aw = A + row0 * H + k0 + t * BT;   // scalar base

        // wave-uniform A chunks, depth-2 prefetch
        float a0[BT], a1[BT];
#pragma unroll
        for (int j = 0; j < 8; ++j)
            *(float4*)&a0[j * 4] = *(const float4*)(Aw + j * 4);

#pragma unroll
        for (int r = 0; r < R; ++r) {
            const float* acur = (r & 1) ? a1 : a0;
            float*       anxt = (r & 1) ? a0 : a1;
            if (r + 1 < R) {
#pragma unroll
                for (int j = 0; j < 8; ++j)
                    *(float4*)&anxt[j * 4] = *(const float4*)(Aw + (long)(r + 1) * H + j * 4);
            }
            float s = acc[r];
#pragma unroll
            for (int g = 0; g < 8; ++g) {
                const float4 w = wf[g];
                s = fmaf(acur[g * 4 + 0], w.x, s);
                s = fmaf(acur[g * 4 + 1], w.y, s);
                s = fmaf(acur[g * 4 + 2], w.z, s);
                s = fmaf(acur[g * 4 + 3], w.w, s);
            }
            acc[r] = s;
        }
    }

    // ---- cross-wave reduce (overlay Lred[4][16][64] on dead W tiles) ----
    __syncthreads();
#pragma unroll
    for (int r = 0; r < R; ++r) lds[wid * (R * E) + r * E + lane] = acc[r];
    __syncthreads();

    const float bv = bias[lane];

    // each wave finalizes 4 rows
#pragma unroll 1
    for (int rr = 0; rr < 4; ++rr) {
        const int  r   = wid * 4 + rr;
        const long row = row0 + r;
        const float logit = ((lds[0 * (R * E) + r * E + lane] + lds[1 * (R * E) + r * E + lane]) +
                             (lds[2 * (R * E) + r * E + lane] + lds[3 * (R * E) + r * E + lane])) + bv;

        probs[row * E + lane] = 1.f / (1.f + __expf(-logit));

        float cur = logit;
        float sv[9]; int si[9];
#pragma unroll
        for (int it = 0; it < 9; ++it) {
            float bp = cur; int bi = lane;
#pragma unroll
            for (int off = 32; off >= 1; off >>= 1) {
                const float op = __shfl_xor(bp, off, 64);
                const int   oi = __shfl_xor(bi, off, 64);
                if (op > bp || (op == bp && oi < bi)) { bp = op; bi = oi; }
            }
            sv[it] = bp; si[it] = bi;
            if (lane == bi) cur = -3e38f;
        }

        float sum = 0.f, mingap = 3e38f;
#pragma unroll
        for (int it = 0; it < TOPK; ++it) {
            sum += 1.f / (1.f + __expf(-sv[it]));
            mingap = fminf(mingap, sv[it] - sv[it + 1]);
        }
        if (lane < TOPK) {
            const float p = 1.f / (1.f + __expf(-sv[lane]));
            weights[row * TOPK + lane] = p / sum;
            indices[row * TOPK + lane] = (float)si[lane];
        }
        if (lane == 0 && mingap < EPS) {
            const unsigned p = atomicAdd(cnt, 1u);
            if (p < (unsigned)T) list[p] = (unsigned)row;
        }
    }
}

// Exact f64 re-resolution: one WAVE per flagged row; coalesced loads; parallel
// butterfly reduce + top-8 (no serial LDS-latency chains).
__global__ __launch_bounds__(256) void fixup_kernel(
    const float* __restrict__ A, const float* __restrict__ Wm,
    const float* __restrict__ bias, float* __restrict__ weights,
    float* __restrict__ indices, const unsigned int* __restrict__ cnt,
    const unsigned int* __restrict__ list, int T)
{
    const int lane = threadIdx.x & 63;
    const int wid  = threadIdx.x >> 6;
    unsigned count = cnt[0];
    if (count > (unsigned)T) count = (unsigned)T;

    for (unsigned idx = blockIdx.x * 4 + wid; idx < count; idx += gridDim.x * 4) {
        const long row = (long)list[idx];
        double myv = 0.0;   // will hold exact logit for expert == lane

#pragma unroll 1
        for (int e = 0; e < E; ++e) {
            double part = 0.0;
#pragma unroll 1
            for (int j = 0; j < 16; ++j) {
                const int k = j * 256 + lane * 4;
                const float4 a = *(const float4*)(A + row * H + k);
                const float4 w = *(const float4*)(Wm + (long)e * H + k);
                part = fma((double)a.x, (double)w.x, part);
                part = fma((double)a.y, (double)w.y, part);
                part = fma((double)a.z, (double)w.z, part);
                part = fma((double)a.w, (double)w.w, part);
            }
#pragma unroll
            for (int off = 32; off >= 1; off >>= 1)
                part += __shfl_xor(part, off, 64);
            if (lane == e) myv = part + (double)bias[e];
        }

        // parallel top-8 on exact f64 logits (lane = expert)
        double cur = myv;
        float sv[TOPK]; int si[TOPK]; float sum = 0.f;
#pragma unroll
        for (int it = 0; it < TOPK; ++it) {
            double bp = cur; int bi = lane;
#pragma unroll
            for (int off = 32; off >= 1; off >>= 1) {
                const double op = __shfl_xor(bp, off, 64);
                const int    oi = __shfl_xor(bi, off, 64);
                if (op > bp || (op == bp && oi < bi)) { bp = op; bi = oi; }
            }
            const float p = 1.f / (1.f + __expf(-(float)bp));
            sv[it] = p; si[it] = bi; sum += p;
            if (lane == bi) cur = -1.0e300;
        }
        if (lane < TOPK) {
            weights[row * TOPK + lane] = sv[lane] / sum;
            indices[row * TOPK + lane] = (float)si[lane];
        }
    }
}

extern "C" void kernel_launch(void* const* d_in, const int* in_sizes, int n_in,
                              void* d_out, int out_size, void* d_ws, size_t ws_size,
                              hipStream_t stream) {
    const float* A    = (const float*)d_in[0];   // [T, H]
    const float* W    = (const float*)d_in[1];   // [E, H]
    const float* bias = (const float*)d_in[2];   // [E]
    const int T = in_sizes[0] / H;               // 16384

    float* out     = (float*)d_out;
    float* weights = out;                          // [T, 8]
    float* indices = out + (size_t)T * TOPK;       // [T, 8] (float-valued)
    float* probs   = out + (size_t)T * 2 * TOPK;   // [T, 64]

    unsigned int* cnt  = (unsigned int*)d_ws;      // [1]
    unsigned int* list = cnt + 8;                  // [T] flagged rows

    hipLaunchKernelGGL(init_cnt_kernel, dim3(1), dim3(64), 0, stream, cnt);
    hipLaunchKernelGGL(router_gemm_kernel, dim3(T / R), dim3(256), 0, stream,
                       A, W, bias, weights, indices, probs, cnt, list, T);
    hipLaunchKernelGGL(fixup_kernel, dim3(256), dim3(256), 0, stream,
                       A, W, bias, weights, indices, cnt, list, T);
}